// Round 11
// baseline (552.267 us; speedup 1.0000x reference)
//
#include <hip/hip_runtime.h>
#include <hip/hip_bf16.h>

#define NNODES 50000
#define NEDGES 800000
#define F_IN 128
#define F_HID 256

using u16 = unsigned short;
using u32 = unsigned int;
using u64 = unsigned long long;
using f32x4 = __attribute__((ext_vector_type(4))) float;
using s16x8 = __attribute__((ext_vector_type(8))) short;

constexpr int B2SHIFT = 9;                         // 512 nodes per coarse bucket
constexpr int NB2 = (NNODES + 511) >> 9;           // 98
constexpr int NBLK = 256;                          // scatter blocks
constexpr int EPB = NEDGES / NBLK;                 // 3125 edges per block (exact)

// ---------------- workspace layout (bytes) ----------------
constexpr size_t OFF_DINV   = 0;          // 200192
constexpr size_t OFF_ROWPTR = 200192;     // 200192
constexpr size_t OFF_CMAT   = 400384;     // 100352 (98*256*4)
constexpr size_t OFF_BTOT   = 500736;     // 1024
constexpr size_t OFF_BBASE  = 501760;     // 1024
constexpr size_t OFF_PAIRS  = 502784;     // 3200000 (800000 u32)
constexpr size_t OFF_PW     = 3702784;    // 3200000 (800000 u32 packed w|src)
constexpr size_t OFF_XB     = 6902784;    // 12800000 (50000x128 bf16)
constexpr size_t OFF_HB     = 19702784;   // 25600000 (50000x256 bf16)
constexpr size_t OFF_AGGB   = 45302784;   // 25600000
constexpr size_t OFF_W1T    = 70902784;   // 65536
constexpr size_t OFF_W2T    = 70968320;   // 131072
constexpr size_t OFF_W3T    = 71099392;   // 131072
// total ~71.2 MB

static __device__ __forceinline__ float b2f(u16 u) {
    union { unsigned int i; float f; } v;
    v.i = ((unsigned int)u) << 16;
    return v.f;
}
static __device__ __forceinline__ u16 f2b(float f) {
    __hip_bfloat16 h = __float2bfloat16(f);  // round-to-nearest
    return __builtin_bit_cast(u16, h);
}

// per-block edge-dtype detect: true => int64 layout.
static __device__ __forceinline__ bool detect_wide(const void* raw) {
    __shared__ int bad;
    if (threadIdx.x == 0) bad = 0;
    __syncthreads();
    unsigned long long v = ((const unsigned long long*)raw)[threadIdx.x & 255];
    if (v >= (unsigned long long)NNODES) atomicAdd(&bad, 1);
    __syncthreads();
    return bad == 0;
}

// ---------------- A: hist (blocks 0..255) + all fp32->bf16 converts (blocks 256..7145) ----------------
__global__ __launch_bounds__(256) void hist_conv(const void* __restrict__ raw, int* __restrict__ cmat,
                                                 const float* __restrict__ x,
                                                 const float* __restrict__ W1, const float* __restrict__ W2,
                                                 const float* __restrict__ W3, u16* __restrict__ xb,
                                                 u16* __restrict__ W1t, u16* __restrict__ W2t,
                                                 u16* __restrict__ W3t) {
    int bid = blockIdx.x;
    int t = threadIdx.x;
    if (bid < NBLK) {
        const bool wide = detect_wide(raw);
        __shared__ int h[NB2];
        if (t < NB2) h[t] = 0;
        __syncthreads();
        const int base = bid * EPB;
        for (int i = t; i < EPB; i += 256) {
            int e = base + i;
            int d = wide ? (int)((const long long*)raw)[NEDGES + e] : ((const int*)raw)[NEDGES + e];
            atomicAdd(&h[d >> B2SHIFT], 1);
        }
        __syncthreads();
        if (t < NB2) cmat[t * NBLK + bid] = h[t];
    } else if (bid < NBLK + 6250) {
        int i = (bid - NBLK) * 256 + t;  // 1,600,000 float4 units exactly
        float4 v = ((const float4*)x)[i];
        ushort4 o;
        o.x = f2b(v.x); o.y = f2b(v.y); o.z = f2b(v.z); o.w = f2b(v.w);
        ((ushort4*)xb)[i] = o;
    } else {
        int idx = (bid - NBLK - 6250) * 256 + t;  // 163840 = 32768 + 65536 + 65536
        if (idx < 32768) {
            int k = idx >> 8, n = idx & 255;
            W1t[n * 128 + k] = f2b(W1[idx]);
        } else if (idx < 98304) {
            int j = idx - 32768;
            int k = j >> 8, n = j & 255;
            W2t[n * 256 + k] = f2b(W2[j]);
        } else {
            int j = idx - 98304;
            int k = j >> 8, n = j & 255;
            W3t[n * 256 + k] = f2b(W3[j]);
        }
    }
}

// B: per-bucket exclusive scan over the 256 block-counts (bucket-local); bucket total out
__global__ __launch_bounds__(256) void offset_kernel(int* __restrict__ cmat, int* __restrict__ btot) {
    __shared__ int s[256];
    int b = blockIdx.x, t = threadIdx.x;
    int v = cmat[b * NBLK + t];
    s[t] = v;
    __syncthreads();
    for (int o = 1; o < 256; o <<= 1) {
        int tmp = (t >= o) ? s[t - o] : 0;
        __syncthreads();
        s[t] += tmp;
        __syncthreads();
    }
    cmat[b * NBLK + t] = s[t] - v;  // exclusive, bucket-local
    if (t == 255) btot[b] = s[255];
}

// C: exclusive scan of 98 bucket totals -> bucket bases
__global__ void bscan_kernel(const int* __restrict__ btot, int* __restrict__ bbase) {
    __shared__ int s[128];
    int t = threadIdx.x;
    int v = (t < NB2) ? btot[t] : 0;
    s[t] = v;
    __syncthreads();
    for (int o = 1; o < 128; o <<= 1) {
        int tmp = (t >= o) ? s[t - o] : 0;
        __syncthreads();
        s[t] += tmp;
        __syncthreads();
    }
    if (t < NB2) bbase[t] = s[t] - v;
}

// D: scatter edges into exact bucket regions; cursors in LDS (block-private)
__global__ __launch_bounds__(256) void scatter_kernel(const void* __restrict__ raw,
                                                      const int* __restrict__ cmat,
                                                      const int* __restrict__ bbase,
                                                      u32* __restrict__ pairs) {
    const bool wide = detect_wide(raw);
    __shared__ int cur[NB2];
    int t = threadIdx.x;
    if (t < NB2) cur[t] = cmat[t * NBLK + blockIdx.x] + bbase[t];
    __syncthreads();
    const int base = blockIdx.x * EPB;
    for (int i = t; i < EPB; i += 256) {
        int e = base + i;
        int s, d;
        if (wide) {
            const long long* p = (const long long*)raw;
            s = (int)p[e];
            d = (int)p[NEDGES + e];
        } else {
            const int* p = (const int*)raw;
            s = p[e];
            d = p[NEDGES + e];
        }
        int pos = atomicAdd(&cur[d >> B2SHIFT], 1);
        pairs[pos] = ((u32)(d & 511) << 16) | (u32)s;  // src < 50000 < 2^16
    }
}

// E: per-bucket degree count (LDS) + 512-wide LDS scan -> row_ptr + dinv
__global__ __launch_bounds__(256) void phase2a(const u32* __restrict__ pairs,
                                               const int* __restrict__ bbase, const int* __restrict__ btot,
                                               int* __restrict__ row_ptr, float* __restrict__ dinv) {
    __shared__ int lcnt[512];
    __shared__ int ssc[512];
    int b = blockIdx.x, t = threadIdx.x;
    int n0 = b << B2SHIFT;
    lcnt[t] = 0; lcnt[t + 256] = 0;
    __syncthreads();
    int p0 = bbase[b], p1 = p0 + btot[b];
    for (int p = p0 + t; p < p1; p += 256)
        atomicAdd(&lcnt[pairs[p] >> 16], 1);
    __syncthreads();
    int c0 = lcnt[t], c1 = lcnt[t + 256];
    ssc[t] = c0; ssc[t + 256] = c1;
    __syncthreads();
    for (int o = 1; o < 512; o <<= 1) {
        int a0 = (t >= o) ? ssc[t - o] : 0;
        int a1 = ssc[t + 256 - o];
        __syncthreads();
        ssc[t] += a0; ssc[t + 256] += a1;
        __syncthreads();
    }
    int na = n0 + t, nb = n0 + t + 256;
    if (na < NNODES) { row_ptr[na] = p0 + ssc[t] - c0;       dinv[na] = rsqrtf((float)c0 + 1.0f); }
    if (nb < NNODES) { row_ptr[nb] = p0 + ssc[t + 256] - c1; dinv[nb] = rsqrtf((float)c1 + 1.0f); }
    if (b == 0 && t == 0) row_ptr[NNODES] = NEDGES;
}

// F: per-bucket ranking -> packed (bf16(dinv[src])<<16 | src) stream
__global__ __launch_bounds__(256) void phase2b(const u32* __restrict__ pairs,
                                               const int* __restrict__ bbase, const int* __restrict__ btot,
                                               const int* __restrict__ row_ptr, const float* __restrict__ dinv,
                                               u32* __restrict__ pw) {
    __shared__ int lcur[512];
    int b = blockIdx.x, t = threadIdx.x;
    int n0 = b << B2SHIFT;
    int na = n0 + t, nb = n0 + t + 256;
    lcur[t]       = (na < NNODES) ? row_ptr[na] : NEDGES;
    lcur[t + 256] = (nb < NNODES) ? row_ptr[nb] : NEDGES;
    __syncthreads();
    int p0 = bbase[b], p1 = p0 + btot[b];
    for (int p = p0 + t; p < p1; p += 256) {
        u32 pk = pairs[p];
        int dl = (int)(pk >> 16);
        int src = (int)(pk & 0xFFFFu);
        int pos = atomicAdd(&lcur[dl], 1);
        pw[pos] = ((u32)f2b(dinv[src]) << 16) | (u32)src;
    }
}

// ---------------- XCD-sliced aggregation ----------------
// out[v] = dv * ( dv*h[v] + sum_e w[e]*h[src[e]] ),  pw[e] = bf16(dinv[src])<<16 | src
// Block b: feature slice (b&7) [F/8 features], node group (b>>3) [16 nodes, 4/wave].
// blockIdx%8 -> XCD round-robin => per-XCD h working set = 50000*(F/8)*2B = 1.6/3.2 MB (L2-fit).
// Wave: 8 edge-slots x 8 feature-lanes (VEC=F/64 feats/lane); cross-slot sum = 3 shfl_xor.
// pw reads + output writes nontemporal (don't evict the h slice).
template <int F>
__global__ __launch_bounds__(256) void agg_sliced(const u16* __restrict__ h,
                                                  const int* __restrict__ row_ptr,
                                                  const u32* __restrict__ pw,
                                                  const float* __restrict__ dinv,
                                                  u16* __restrict__ outb) {
    constexpr int VEC = F / 64;        // features per lane (2 or 4)
    constexpr int SLW = F / 8;         // slice width in features
    const int slice = blockIdx.x & 7;
    const int gidx  = blockIdx.x >> 3;
    const int lane = threadIdx.x & 63;
    const int w = threadIdx.x >> 6;
    const int slot = lane >> 3;        // edge slot 0..7
    const int fl = lane & 7;           // feature lane 0..7
    const int fbase = slice * SLW + fl * VEC;

    for (int i = 0; i < 4; ++i) {
        const int v = gidx * 16 + w * 4 + i;   // 50000 = 16*3125 exact
        const int e0 = row_ptr[v], e1 = row_ptr[v + 1];
        const float dv = dinv[v];
        float acc[VEC];
        {   // self term: only slot 0 contributes (weight dv), others weight 0
            const u16* p = h + (size_t)v * F + fbase;
            float ws = (slot == 0) ? dv : 0.f;
            if constexpr (VEC == 4) {
                ushort4 t = *(const ushort4*)p;
                acc[0] = ws * b2f(t.x); acc[1] = ws * b2f(t.y);
                acc[2] = ws * b2f(t.z); acc[3] = ws * b2f(t.w);
            } else {
                ushort2 t = *(const ushort2*)p;
                acc[0] = ws * b2f(t.x); acc[1] = ws * b2f(t.y);
            }
        }
        // per-slot edge loop, unroll-2 (16 edges in flight per wave)
        for (int e = e0 + slot; e < e1; e += 16) {
            int ib = (e + 8 < e1) ? e + 8 : e1 - 1;
            u32 pa = __builtin_nontemporal_load(pw + e);
            u32 pb = __builtin_nontemporal_load(pw + ib);
            int ca = (int)(pa & 0xFFFFu), cb = (int)(pb & 0xFFFFu);
            float wa = b2f((u16)(pa >> 16));
            float wb = (e + 8 < e1) ? b2f((u16)(pb >> 16)) : 0.f;
            const u16* p1 = h + (size_t)ca * F + fbase;
            const u16* p2 = h + (size_t)cb * F + fbase;
            if constexpr (VEC == 4) {
                ushort4 ra = *(const ushort4*)p1;
                ushort4 rb = *(const ushort4*)p2;
                acc[0] += wa * b2f(ra.x) + wb * b2f(rb.x);
                acc[1] += wa * b2f(ra.y) + wb * b2f(rb.y);
                acc[2] += wa * b2f(ra.z) + wb * b2f(rb.z);
                acc[3] += wa * b2f(ra.w) + wb * b2f(rb.w);
            } else {
                ushort2 ra = *(const ushort2*)p1;
                ushort2 rb = *(const ushort2*)p2;
                acc[0] += wa * b2f(ra.x) + wb * b2f(rb.x);
                acc[1] += wa * b2f(ra.y) + wb * b2f(rb.y);
            }
        }
        // cross-slot reduce (slot bits are lane bits 3..5)
#pragma unroll
        for (int q = 0; q < VEC; ++q) {
            acc[q] += __shfl_xor(acc[q], 8);
            acc[q] += __shfl_xor(acc[q], 16);
            acc[q] += __shfl_xor(acc[q], 32);
        }
        if (slot == 0) {
            u16* o = outb + (size_t)v * F + fbase;
            if constexpr (VEC == 4) {
                ushort4 t;
                t.x = f2b(dv * acc[0]); t.y = f2b(dv * acc[1]);
                t.z = f2b(dv * acc[2]); t.w = f2b(dv * acc[3]);
                __builtin_nontemporal_store(__builtin_bit_cast(u64, t), (u64*)o);
            } else {
                ushort2 t;
                t.x = f2b(dv * acc[0]); t.y = f2b(dv * acc[1]);
                __builtin_nontemporal_store(__builtin_bit_cast(u32, t), (u32*)o);
            }
        }
    }
}

// ---------------- bf16 MFMA GEMM: out[M x 256] = A[M x KT] @ W[KT x 256] + b ----------------
template <int KT, bool RELU, bool OUT_BF16>
__global__ __launch_bounds__(256) void gemm_mfma(const u16* __restrict__ A, const u16* __restrict__ Wt,
                                                 const float* __restrict__ bias, void* __restrict__ outp,
                                                 int M) {
    constexpr int BM = 128, BN = 128, BK = 32;
    __shared__ __align__(16) u16 As[BM * BK];
    __shared__ __align__(16) u16 Bs[BN * BK];
    const int tid = threadIdx.x;
    const int lane = tid & 63, wid = tid >> 6;
    const int l15 = lane & 15, lhi = lane >> 4;
    const int m0 = blockIdx.x * BM, n0 = blockIdx.y * BN;
    const int wr = (wid >> 1) * 64, wc = (wid & 1) * 64;

    f32x4 acc[4][4] = {};

    const int sr = tid >> 1;        // staging row 0..127
    const int sc2 = (tid & 1) * 2;  // staging chunk base (0 or 2)

    for (int k0 = 0; k0 < KT; k0 += BK) {
        uint4 av0, av1, bv0, bv1;
        int ar = m0 + sr;
        if (ar < M) {
            const uint4* ap = (const uint4*)(A + (size_t)ar * KT + k0 + sc2 * 8);
            av0 = ap[0]; av1 = ap[1];
        } else {
            av0 = make_uint4(0, 0, 0, 0); av1 = av0;
        }
        const uint4* bp = (const uint4*)(Wt + (size_t)(n0 + sr) * KT + k0 + sc2 * 8);
        bv0 = bp[0]; bv1 = bp[1];

        __syncthreads();
        *(uint4*)&As[sr * BK + ((sc2 ^ (sr & 3)) * 8)]       = av0;
        *(uint4*)&As[sr * BK + (((sc2 + 1) ^ (sr & 3)) * 8)] = av1;
        *(uint4*)&Bs[sr * BK + ((sc2 ^ (sr & 3)) * 8)]       = bv0;
        *(uint4*)&Bs[sr * BK + (((sc2 + 1) ^ (sr & 3)) * 8)] = bv1;
        __syncthreads();

        s16x8 af[4], bfr[4];
#pragma unroll
        for (int m = 0; m < 4; ++m) {
            int r = wr + m * 16 + l15;
            af[m] = *(const s16x8*)&As[r * BK + ((lhi ^ (r & 3)) * 8)];
        }
#pragma unroll
        for (int n = 0; n < 4; ++n) {
            int r = wc + n * 16 + l15;
            bfr[n] = *(const s16x8*)&Bs[r * BK + ((lhi ^ (r & 3)) * 8)];
        }
#pragma unroll
        for (int m = 0; m < 4; ++m)
#pragma unroll
            for (int n = 0; n < 4; ++n)
                acc[m][n] = __builtin_amdgcn_mfma_f32_16x16x32_bf16(af[m], bfr[n], acc[m][n], 0, 0, 0);
    }

    // epilogue: C/D layout col = lane&15, row = (lane>>4)*4 + reg
#pragma unroll
    for (int n = 0; n < 4; ++n) {
        int gcol = n0 + wc + n * 16 + l15;
        float bb = bias[gcol];
#pragma unroll
        for (int m = 0; m < 4; ++m) {
            int gr0 = m0 + wr + m * 16 + lhi * 4;
#pragma unroll
            for (int r = 0; r < 4; ++r) {
                int gr = gr0 + r;
                if (gr >= M) continue;
                float vv = acc[m][n][r] + bb;
                if (RELU) vv = vv > 0.f ? vv : 0.f;
                if (OUT_BF16)
                    ((u16*)outp)[(size_t)gr * 256 + gcol] = f2b(vv);
                else
                    ((float*)outp)[(size_t)gr * 256 + gcol] = vv;
            }
        }
    }
}

// ---------------- launch ----------------
extern "C" void kernel_launch(void* const* d_in, const int* in_sizes, int n_in,
                              void* d_out, int out_size, void* d_ws, size_t ws_size,
                              hipStream_t stream) {
    const float* x  = (const float*)d_in[0];
    const void* edges = d_in[1];
    const float* W1 = (const float*)d_in[2];
    const float* b1 = (const float*)d_in[3];
    const float* W2 = (const float*)d_in[4];
    const float* b2 = (const float*)d_in[5];
    const float* W3 = (const float*)d_in[6];
    const float* b3 = (const float*)d_in[7];
    float* out = (float*)d_out;

    char* ws = (char*)d_ws;
    float* dinv   = (float*)(ws + OFF_DINV);
    int*   rowptr = (int*)(ws + OFF_ROWPTR);
    int*   cmat   = (int*)(ws + OFF_CMAT);
    int*   btot   = (int*)(ws + OFF_BTOT);
    int*   bbase  = (int*)(ws + OFF_BBASE);
    u32*   pairs  = (u32*)(ws + OFF_PAIRS);
    u32*   pw     = (u32*)(ws + OFF_PW);
    u16*   xb     = (u16*)(ws + OFF_XB);
    u16*   hb     = (u16*)(ws + OFF_HB);
    u16*   aggb   = (u16*)(ws + OFF_AGGB);
    u16*   W1t    = (u16*)(ws + OFF_W1T);
    u16*   W2t    = (u16*)(ws + OFF_W2T);
    u16*   W3t    = (u16*)(ws + OFF_W3T);

    // CSR build + converts (hist+convert merged)
    hist_conv<<<NBLK + 6250 + 640, 256, 0, stream>>>(edges, cmat, x, W1, W2, W3, xb, W1t, W2t, W3t);
    offset_kernel<<<NB2, 256, 0, stream>>>(cmat, btot);
    bscan_kernel<<<1, 128, 0, stream>>>(btot, bbase);
    scatter_kernel<<<NBLK, 256, 0, stream>>>(edges, cmat, bbase, pairs);
    phase2a<<<NB2, 256, 0, stream>>>(pairs, bbase, btot, rowptr, dinv);
    phase2b<<<NB2, 256, 0, stream>>>(pairs, bbase, btot, rowptr, dinv, pw);

    const int AGG_GRID = 8 * (NNODES / 16);  // 8 slices x 3125 node groups = 25000
    dim3 ggrid((NNODES + 127) / 128, 2);

    // layer 1
    agg_sliced<F_IN><<<AGG_GRID, 256, 0, stream>>>(xb, rowptr, pw, dinv, aggb);
    gemm_mfma<F_IN, true, true><<<ggrid, 256, 0, stream>>>(aggb, W1t, b1, hb, NNODES);

    // layer 2
    agg_sliced<F_HID><<<AGG_GRID, 256, 0, stream>>>(hb, rowptr, pw, dinv, aggb);
    gemm_mfma<F_HID, true, true><<<ggrid, 256, 0, stream>>>(aggb, W2t, b2, hb, NNODES);

    // layer 3
    agg_sliced<F_HID><<<AGG_GRID, 256, 0, stream>>>(hb, rowptr, pw, dinv, aggb);
    gemm_mfma<F_HID, false, false><<<ggrid, 256, 0, stream>>>(aggb, W3t, b3, out, NNODES);
}

// Round 12
// 286.969 us; speedup vs baseline: 1.9245x; 1.9245x over previous
//
#include <hip/hip_runtime.h>
#include <hip/hip_bf16.h>

#define NNODES 50000
#define NEDGES 800000
#define F_IN 128
#define F_HID 256

using u16 = unsigned short;
using u32 = unsigned int;
using u64 = unsigned long long;
using f32x4 = __attribute__((ext_vector_type(4))) float;
using s16x8 = __attribute__((ext_vector_type(8))) short;

constexpr int B2SHIFT = 9;                         // 512 nodes per coarse bucket
constexpr int NB2 = (NNODES + 511) >> 9;           // 98
constexpr int NBLK = 256;                          // scatter blocks
constexpr int EPB = NEDGES / NBLK;                 // 3125 edges per block (exact)

// ---------------- workspace layout (bytes) ----------------
constexpr size_t OFF_DINV   = 0;          // 200192
constexpr size_t OFF_ROWPTR = 200192;     // 200192
constexpr size_t OFF_CMAT   = 400384;     // 100352 (98*256*4)
constexpr size_t OFF_BTOT   = 500736;     // 1024
constexpr size_t OFF_BBASE  = 501760;     // 1024
constexpr size_t OFF_PAIRS  = 502784;     // 3200000 (800000 u32)
constexpr size_t OFF_COL16  = 3702784;    // 1600000 (800000 u16)
constexpr size_t OFF_XG     = 5302784;    // 12800000 (50000x128 bf16, pre-scaled by dinv)
constexpr size_t OFF_HB     = 18102784;   // 25600000 (50000x256 bf16, pre-scaled)
constexpr size_t OFF_AGGB   = 43702784;   // 25600000
constexpr size_t OFF_W1T    = 69302784;   // 65536
constexpr size_t OFF_W2T    = 69368320;   // 131072
constexpr size_t OFF_W3T    = 69499392;   // 131072
// total ~69.6 MB

static __device__ __forceinline__ float b2f(u16 u) {
    union { unsigned int i; float f; } v;
    v.i = ((unsigned int)u) << 16;
    return v.f;
}
static __device__ __forceinline__ u16 f2b(float f) {
    __hip_bfloat16 h = __float2bfloat16(f);  // round-to-nearest
    return __builtin_bit_cast(u16, h);
}

// per-block edge-dtype detect: true => int64 layout.
static __device__ __forceinline__ bool detect_wide(const void* raw) {
    __shared__ int bad;
    if (threadIdx.x == 0) bad = 0;
    __syncthreads();
    unsigned long long v = ((const unsigned long long*)raw)[threadIdx.x & 255];
    if (v >= (unsigned long long)NNODES) atomicAdd(&bad, 1);
    __syncthreads();
    return bad == 0;
}

// ---------------- A: hist (blocks 0..255) + W transposes (blocks 256..895) ----------------
__global__ __launch_bounds__(256) void hist_conv(const void* __restrict__ raw, int* __restrict__ cmat,
                                                 const float* __restrict__ W1, const float* __restrict__ W2,
                                                 const float* __restrict__ W3,
                                                 u16* __restrict__ W1t, u16* __restrict__ W2t,
                                                 u16* __restrict__ W3t) {
    int bid = blockIdx.x;
    int t = threadIdx.x;
    if (bid < NBLK) {
        const bool wide = detect_wide(raw);
        __shared__ int h[NB2];
        if (t < NB2) h[t] = 0;
        __syncthreads();
        const int base = bid * EPB;
        for (int i = t; i < EPB; i += 256) {
            int e = base + i;
            int d = wide ? (int)((const long long*)raw)[NEDGES + e] : ((const int*)raw)[NEDGES + e];
            atomicAdd(&h[d >> B2SHIFT], 1);
        }
        __syncthreads();
        if (t < NB2) cmat[t * NBLK + bid] = h[t];
    } else {
        int idx = (bid - NBLK) * 256 + t;  // 163840 = 32768 + 65536 + 65536
        if (idx < 32768) {
            int k = idx >> 8, n = idx & 255;
            W1t[n * 128 + k] = f2b(W1[idx]);
        } else if (idx < 98304) {
            int j = idx - 32768;
            int k = j >> 8, n = j & 255;
            W2t[n * 256 + k] = f2b(W2[j]);
        } else if (idx < 163840) {
            int j = idx - 98304;
            int k = j >> 8, n = j & 255;
            W3t[n * 256 + k] = f2b(W3[j]);
        }
    }
}

// B: per-bucket exclusive scan over the 256 block-counts (bucket-local); bucket total out
__global__ __launch_bounds__(256) void offset_kernel(int* __restrict__ cmat, int* __restrict__ btot) {
    __shared__ int s[256];
    int b = blockIdx.x, t = threadIdx.x;
    int v = cmat[b * NBLK + t];
    s[t] = v;
    __syncthreads();
    for (int o = 1; o < 256; o <<= 1) {
        int tmp = (t >= o) ? s[t - o] : 0;
        __syncthreads();
        s[t] += tmp;
        __syncthreads();
    }
    cmat[b * NBLK + t] = s[t] - v;  // exclusive, bucket-local
    if (t == 255) btot[b] = s[255];
}

// C: exclusive scan of 98 bucket totals -> bucket bases
__global__ void bscan_kernel(const int* __restrict__ btot, int* __restrict__ bbase) {
    __shared__ int s[128];
    int t = threadIdx.x;
    int v = (t < NB2) ? btot[t] : 0;
    s[t] = v;
    __syncthreads();
    for (int o = 1; o < 128; o <<= 1) {
        int tmp = (t >= o) ? s[t - o] : 0;
        __syncthreads();
        s[t] += tmp;
        __syncthreads();
    }
    if (t < NB2) bbase[t] = s[t] - v;
}

// D: scatter edges into exact bucket regions; cursors in LDS (block-private)
__global__ __launch_bounds__(256) void scatter_kernel(const void* __restrict__ raw,
                                                      const int* __restrict__ cmat,
                                                      const int* __restrict__ bbase,
                                                      u32* __restrict__ pairs) {
    const bool wide = detect_wide(raw);
    __shared__ int cur[NB2];
    int t = threadIdx.x;
    if (t < NB2) cur[t] = cmat[t * NBLK + blockIdx.x] + bbase[t];
    __syncthreads();
    const int base = blockIdx.x * EPB;
    for (int i = t; i < EPB; i += 256) {
        int e = base + i;
        int s, d;
        if (wide) {
            const long long* p = (const long long*)raw;
            s = (int)p[e];
            d = (int)p[NEDGES + e];
        } else {
            const int* p = (const int*)raw;
            s = p[e];
            d = p[NEDGES + e];
        }
        int pos = atomicAdd(&cur[d >> B2SHIFT], 1);
        pairs[pos] = ((u32)(d & 511) << 16) | (u32)s;  // src < 50000 < 2^16
    }
}

// E (fused): per-bucket degree count + 512-wide LDS scan -> row_ptr + dinv,
// then in-LDS cursor ranking -> u16 col stream. One pass kernel, no dinv gather needed.
__global__ __launch_bounds__(256) void phase2_fused(const u32* __restrict__ pairs,
                                                    const int* __restrict__ bbase, const int* __restrict__ btot,
                                                    int* __restrict__ row_ptr, float* __restrict__ dinv,
                                                    u16* __restrict__ col) {
    __shared__ int lcnt[512];
    __shared__ int ssc[512];
    int b = blockIdx.x, t = threadIdx.x;
    int n0 = b << B2SHIFT;
    lcnt[t] = 0; lcnt[t + 256] = 0;
    __syncthreads();
    int p0 = bbase[b], p1 = p0 + btot[b];
    for (int p = p0 + t; p < p1; p += 256)
        atomicAdd(&lcnt[pairs[p] >> 16], 1);
    __syncthreads();
    int c0 = lcnt[t], c1 = lcnt[t + 256];
    ssc[t] = c0; ssc[t + 256] = c1;
    __syncthreads();
    for (int o = 1; o < 512; o <<= 1) {
        int a0 = (t >= o) ? ssc[t - o] : 0;
        int a1 = ssc[t + 256 - o];  // t+256 >= o always (o <= 256)
        __syncthreads();
        ssc[t] += a0; ssc[t + 256] += a1;
        __syncthreads();
    }
    int ex0 = ssc[t] - c0, ex1 = ssc[t + 256] - c1;  // exclusive, bucket-local
    int na = n0 + t, nb = n0 + t + 256;
    if (na < NNODES) { row_ptr[na] = p0 + ex0; dinv[na] = rsqrtf((float)c0 + 1.0f); }
    if (nb < NNODES) { row_ptr[nb] = p0 + ex1; dinv[nb] = rsqrtf((float)c1 + 1.0f); }
    if (b == 0 && t == 0) row_ptr[NNODES] = NEDGES;
    // reuse lcnt as global cursors
    lcnt[t] = p0 + ex0;
    lcnt[t + 256] = p0 + ex1;
    __syncthreads();
    for (int p = p0 + t; p < p1; p += 256) {
        u32 pk = pairs[p];
        int dl = (int)(pk >> 16);
        int pos = atomicAdd(&lcnt[dl], 1);
        col[pos] = (u16)(pk & 0xFFFFu);
    }
}

// F: xg[v] = dinv[v] * x[v]  (fp32 -> bf16, pre-scaled feature table)
__global__ __launch_bounds__(256) void xscale_kernel(const float* __restrict__ x,
                                                     const float* __restrict__ dinv,
                                                     u16* __restrict__ xg) {
    int i = blockIdx.x * 256 + threadIdx.x;  // 1,600,000 float4 units exactly
    float dv = dinv[i >> 5];                 // 32 float4 per 128-wide row
    float4 v = ((const float4*)x)[i];
    ushort4 o;
    o.x = f2b(dv * v.x); o.y = f2b(dv * v.y); o.z = f2b(dv * v.z); o.w = f2b(dv * v.w);
    ((ushort4*)xg)[i] = o;
}

// ---------------- aggregation on pre-scaled table ----------------
// agg[v] = dv * ( g[v] + sum_e g[col[e]] );  g = dinv.*h, dv = dinv[v]
template <int F>
__global__ __launch_bounds__(256) void agg_kernel(const u16* __restrict__ g,
                                                  const int* __restrict__ row_ptr,
                                                  const u16* __restrict__ col,
                                                  const float* __restrict__ dinv,
                                                  u16* __restrict__ outb) {
    constexpr int VEC = F / 64;  // 2 (F=128) or 4 (F=256) bf16 per lane
    int lane = threadIdx.x & 63;
    int v = __builtin_amdgcn_readfirstlane((int)(blockIdx.x * 4 + (threadIdx.x >> 6)));
    const size_t lo = (size_t)lane * VEC;

    const int e0 = row_ptr[v], e1 = row_ptr[v + 1];
    const float dv = dinv[v];
    float acc[VEC];
    {
        const u16* p = g + (size_t)v * F + lo;
        if constexpr (VEC == 4) {
            ushort4 t = *(const ushort4*)p;
            acc[0] = b2f(t.x); acc[1] = b2f(t.y); acc[2] = b2f(t.z); acc[3] = b2f(t.w);
        } else {
            ushort2 t = *(const ushort2*)p;
            acc[0] = b2f(t.x); acc[1] = b2f(t.y);
        }
    }
    // unconditional clamped unroll-8; OOB slots get weight 0 (duplicates must not double-count)
    for (int e = e0; e < e1; e += 8) {
        int   c[8];
        float w[8];
#pragma unroll
        for (int u = 0; u < 8; ++u) {
            int idx = e + u;
            int cl = idx < e1 ? idx : e1 - 1;  // safe: loop entered only if e1 > e0
            c[u] = (int)col[cl];
            w[u] = idx < e1 ? 1.0f : 0.0f;
        }
        if constexpr (VEC == 4) {
            ushort4 r[8];
#pragma unroll
            for (int u = 0; u < 8; ++u)
                r[u] = *(const ushort4*)(g + (size_t)c[u] * F + lo);
#pragma unroll
            for (int u = 0; u < 8; ++u) {
                acc[0] += w[u] * b2f(r[u].x);
                acc[1] += w[u] * b2f(r[u].y);
                acc[2] += w[u] * b2f(r[u].z);
                acc[3] += w[u] * b2f(r[u].w);
            }
        } else {
            ushort2 r[8];
#pragma unroll
            for (int u = 0; u < 8; ++u)
                r[u] = *(const ushort2*)(g + (size_t)c[u] * F + lo);
#pragma unroll
            for (int u = 0; u < 8; ++u) {
                acc[0] += w[u] * b2f(r[u].x);
                acc[1] += w[u] * b2f(r[u].y);
            }
        }
    }
    u16* o = outb + (size_t)v * F + lo;
    if constexpr (VEC == 4) {
        ushort4 t;
        t.x = f2b(dv * acc[0]); t.y = f2b(dv * acc[1]); t.z = f2b(dv * acc[2]); t.w = f2b(dv * acc[3]);
        *(ushort4*)o = t;
    } else {
        ushort2 t;
        t.x = f2b(dv * acc[0]); t.y = f2b(dv * acc[1]);
        *(ushort2*)o = t;
    }
}

// ---------------- bf16 MFMA GEMM: out[M x 256] = A[M x KT] @ W[KT x 256] + b ----------------
// SCALE_OUT: multiply output row gr by dinv[gr] (produces the next pre-scaled table g).
template <int KT, bool RELU, bool OUT_BF16, bool SCALE_OUT>
__global__ __launch_bounds__(256) void gemm_mfma(const u16* __restrict__ A, const u16* __restrict__ Wt,
                                                 const float* __restrict__ bias,
                                                 const float* __restrict__ dinv,
                                                 void* __restrict__ outp, int M) {
    constexpr int BM = 128, BN = 128, BK = 32;
    __shared__ __align__(16) u16 As[BM * BK];
    __shared__ __align__(16) u16 Bs[BN * BK];
    const int tid = threadIdx.x;
    const int lane = tid & 63, wid = tid >> 6;
    const int l15 = lane & 15, lhi = lane >> 4;
    const int m0 = blockIdx.x * BM, n0 = blockIdx.y * BN;
    const int wr = (wid >> 1) * 64, wc = (wid & 1) * 64;

    f32x4 acc[4][4] = {};

    const int sr = tid >> 1;        // staging row 0..127
    const int sc2 = (tid & 1) * 2;  // staging chunk base (0 or 2)

    for (int k0 = 0; k0 < KT; k0 += BK) {
        uint4 av0, av1, bv0, bv1;
        int ar = m0 + sr;
        if (ar < M) {
            const uint4* ap = (const uint4*)(A + (size_t)ar * KT + k0 + sc2 * 8);
            av0 = ap[0]; av1 = ap[1];
        } else {
            av0 = make_uint4(0, 0, 0, 0); av1 = av0;
        }
        const uint4* bp = (const uint4*)(Wt + (size_t)(n0 + sr) * KT + k0 + sc2 * 8);
        bv0 = bp[0]; bv1 = bp[1];

        __syncthreads();
        *(uint4*)&As[sr * BK + ((sc2 ^ (sr & 3)) * 8)]       = av0;
        *(uint4*)&As[sr * BK + (((sc2 + 1) ^ (sr & 3)) * 8)] = av1;
        *(uint4*)&Bs[sr * BK + ((sc2 ^ (sr & 3)) * 8)]       = bv0;
        *(uint4*)&Bs[sr * BK + (((sc2 + 1) ^ (sr & 3)) * 8)] = bv1;
        __syncthreads();

        s16x8 af[4], bfr[4];
#pragma unroll
        for (int m = 0; m < 4; ++m) {
            int r = wr + m * 16 + l15;
            af[m] = *(const s16x8*)&As[r * BK + ((lhi ^ (r & 3)) * 8)];
        }
#pragma unroll
        for (int n = 0; n < 4; ++n) {
            int r = wc + n * 16 + l15;
            bfr[n] = *(const s16x8*)&Bs[r * BK + ((lhi ^ (r & 3)) * 8)];
        }
#pragma unroll
        for (int m = 0; m < 4; ++m)
#pragma unroll
            for (int n = 0; n < 4; ++n)
                acc[m][n] = __builtin_amdgcn_mfma_f32_16x16x32_bf16(af[m], bfr[n], acc[m][n], 0, 0, 0);
    }

    // row scales (hoisted): gr = m0 + wr + m*16 + lhi*4 + r
    float dvr[4][4];
    if (SCALE_OUT) {
#pragma unroll
        for (int m = 0; m < 4; ++m)
#pragma unroll
            for (int r = 0; r < 4; ++r) {
                int gr = m0 + wr + m * 16 + lhi * 4 + r;
                dvr[m][r] = (gr < M) ? dinv[gr] : 1.0f;
            }
    }

    // epilogue: C/D layout col = lane&15, row = (lane>>4)*4 + reg
#pragma unroll
    for (int n = 0; n < 4; ++n) {
        int gcol = n0 + wc + n * 16 + l15;
        float bb = bias[gcol];
#pragma unroll
        for (int m = 0; m < 4; ++m) {
            int gr0 = m0 + wr + m * 16 + lhi * 4;
#pragma unroll
            for (int r = 0; r < 4; ++r) {
                int gr = gr0 + r;
                if (gr >= M) continue;
                float vv = acc[m][n][r] + bb;
                if (RELU) vv = vv > 0.f ? vv : 0.f;
                if (SCALE_OUT) vv *= dvr[m][r];
                if (OUT_BF16)
                    ((u16*)outp)[(size_t)gr * 256 + gcol] = f2b(vv);
                else
                    ((float*)outp)[(size_t)gr * 256 + gcol] = vv;
            }
        }
    }
}

// ---------------- launch ----------------
extern "C" void kernel_launch(void* const* d_in, const int* in_sizes, int n_in,
                              void* d_out, int out_size, void* d_ws, size_t ws_size,
                              hipStream_t stream) {
    const float* x  = (const float*)d_in[0];
    const void* edges = d_in[1];
    const float* W1 = (const float*)d_in[2];
    const float* b1 = (const float*)d_in[3];
    const float* W2 = (const float*)d_in[4];
    const float* b2 = (const float*)d_in[5];
    const float* W3 = (const float*)d_in[6];
    const float* b3 = (const float*)d_in[7];
    float* out = (float*)d_out;

    char* ws = (char*)d_ws;
    float* dinv   = (float*)(ws + OFF_DINV);
    int*   rowptr = (int*)(ws + OFF_ROWPTR);
    int*   cmat   = (int*)(ws + OFF_CMAT);
    int*   btot   = (int*)(ws + OFF_BTOT);
    int*   bbase  = (int*)(ws + OFF_BBASE);
    u32*   pairs  = (u32*)(ws + OFF_PAIRS);
    u16*   col16  = (u16*)(ws + OFF_COL16);
    u16*   xg     = (u16*)(ws + OFF_XG);
    u16*   hb     = (u16*)(ws + OFF_HB);
    u16*   aggb   = (u16*)(ws + OFF_AGGB);
    u16*   W1t    = (u16*)(ws + OFF_W1T);
    u16*   W2t    = (u16*)(ws + OFF_W2T);
    u16*   W3t    = (u16*)(ws + OFF_W3T);

    // CSR build + weight converts
    hist_conv<<<NBLK + 640, 256, 0, stream>>>(edges, cmat, W1, W2, W3, W1t, W2t, W3t);
    offset_kernel<<<NB2, 256, 0, stream>>>(cmat, btot);
    bscan_kernel<<<1, 128, 0, stream>>>(btot, bbase);
    scatter_kernel<<<NBLK, 256, 0, stream>>>(edges, cmat, bbase, pairs);
    phase2_fused<<<NB2, 256, 0, stream>>>(pairs, bbase, btot, rowptr, dinv, col16);

    // pre-scaled input table
    xscale_kernel<<<6250, 256, 0, stream>>>(x, dinv, xg);

    const int AGG_GRID = NNODES / 4;  // 12500
    dim3 ggrid((NNODES + 127) / 128, 2);

    // layer 1: aggb = dinv.*(A_sum xg); hb = dinv.*relu(aggb@W1+b1)
    agg_kernel<F_IN><<<AGG_GRID, 256, 0, stream>>>(xg, rowptr, col16, dinv, aggb);
    gemm_mfma<F_IN, true, true, true><<<ggrid, 256, 0, stream>>>(aggb, W1t, b1, dinv, hb, NNODES);

    // layer 2
    agg_kernel<F_HID><<<AGG_GRID, 256, 0, stream>>>(hb, rowptr, col16, dinv, aggb);
    gemm_mfma<F_HID, true, true, true><<<ggrid, 256, 0, stream>>>(aggb, W2t, b2, dinv, hb, NNODES);

    // layer 3: plain fp32 output
    agg_kernel<F_HID><<<AGG_GRID, 256, 0, stream>>>(hb, rowptr, col16, dinv, aggb);
    gemm_mfma<F_HID, false, false, false><<<ggrid, 256, 0, stream>>>(aggb, W3t, b3, dinv, out, NNODES);
}

// Round 13
// 276.441 us; speedup vs baseline: 1.9978x; 1.0381x over previous
//
#include <hip/hip_runtime.h>
#include <hip/hip_bf16.h>

#define NNODES 50000
#define NEDGES 800000
#define F_IN 128
#define F_HID 256

using u16 = unsigned short;
using u32 = unsigned int;
using f32x4 = __attribute__((ext_vector_type(4))) float;
using s16x8 = __attribute__((ext_vector_type(8))) short;

constexpr int B2SHIFT = 9;                         // 512 nodes per coarse bucket
constexpr int NB2 = (NNODES + 511) >> 9;           // 98
constexpr int NBLK = 256;                          // scatter blocks
constexpr int EPB = NEDGES / NBLK;                 // 3125 edges per block (exact)

// ---------------- workspace layout (bytes) ----------------
constexpr size_t OFF_DINV   = 0;          // 200192
constexpr size_t OFF_ROWPTR = 200192;     // 200192
constexpr size_t OFF_CMAT   = 400384;     // 100352 (98*256*4)
constexpr size_t OFF_BTOT   = 500736;     // 1024
constexpr size_t OFF_PAIRS  = 501760;     // 3200000 (800000 u32)
constexpr size_t OFF_PW     = 3701760;    // 3200000 (800000 u32 packed w|src)
constexpr size_t OFF_XB     = 6901760;    // 12800000 (50000x128 bf16)
constexpr size_t OFF_HB     = 19701760;   // 25600000 (50000x256 bf16)
constexpr size_t OFF_AGGB   = 45301760;   // 25600000
constexpr size_t OFF_W1T    = 70901760;   // 65536
constexpr size_t OFF_W2T    = 70967296;   // 131072
constexpr size_t OFF_W3T    = 71098368;   // 131072
// total ~71.2 MB

static __device__ __forceinline__ float b2f(u16 u) {
    union { unsigned int i; float f; } v;
    v.i = ((unsigned int)u) << 16;
    return v.f;
}
static __device__ __forceinline__ u16 f2b(float f) {
    __hip_bfloat16 h = __float2bfloat16(f);  // round-to-nearest
    return __builtin_bit_cast(u16, h);
}

// per-block edge-dtype detect: true => int64 layout.
static __device__ __forceinline__ bool detect_wide(const void* raw) {
    __shared__ int bad;
    if (threadIdx.x == 0) bad = 0;
    __syncthreads();
    unsigned long long v = ((const unsigned long long*)raw)[threadIdx.x & 255];
    if (v >= (unsigned long long)NNODES) atomicAdd(&bad, 1);
    __syncthreads();
    return bad == 0;
}

// ---------------- A: hist (blocks 0..255) + all fp32->bf16 converts (blocks 256..7145) ----------------
__global__ __launch_bounds__(256) void hist_conv(const void* __restrict__ raw, int* __restrict__ cmat,
                                                 const float* __restrict__ x,
                                                 const float* __restrict__ W1, const float* __restrict__ W2,
                                                 const float* __restrict__ W3, u16* __restrict__ xb,
                                                 u16* __restrict__ W1t, u16* __restrict__ W2t,
                                                 u16* __restrict__ W3t) {
    int bid = blockIdx.x;
    int t = threadIdx.x;
    if (bid < NBLK) {
        const bool wide = detect_wide(raw);
        __shared__ int h[NB2];
        if (t < NB2) h[t] = 0;
        __syncthreads();
        const int base = bid * EPB;
        for (int i = t; i < EPB; i += 256) {
            int e = base + i;
            int d = wide ? (int)((const long long*)raw)[NEDGES + e] : ((const int*)raw)[NEDGES + e];
            atomicAdd(&h[d >> B2SHIFT], 1);
        }
        __syncthreads();
        if (t < NB2) cmat[t * NBLK + bid] = h[t];
    } else if (bid < NBLK + 6250) {
        int i = (bid - NBLK) * 256 + t;  // 1,600,000 float4 units exactly
        float4 v = ((const float4*)x)[i];
        ushort4 o;
        o.x = f2b(v.x); o.y = f2b(v.y); o.z = f2b(v.z); o.w = f2b(v.w);
        ((ushort4*)xb)[i] = o;
    } else {
        int idx = (bid - NBLK - 6250) * 256 + t;  // 163840 = 32768 + 65536 + 65536
        if (idx < 32768) {
            int k = idx >> 8, n = idx & 255;
            W1t[n * 128 + k] = f2b(W1[idx]);
        } else if (idx < 98304) {
            int j = idx - 32768;
            int k = j >> 8, n = j & 255;
            W2t[n * 256 + k] = f2b(W2[j]);
        } else {
            int j = idx - 98304;
            int k = j >> 8, n = j & 255;
            W3t[n * 256 + k] = f2b(W3[j]);
        }
    }
}

// B: per-bucket exclusive scan over the 256 block-counts (bucket-local); bucket total out
__global__ __launch_bounds__(256) void offset_kernel(int* __restrict__ cmat, int* __restrict__ btot) {
    __shared__ int s[256];
    int b = blockIdx.x, t = threadIdx.x;
    int v = cmat[b * NBLK + t];
    s[t] = v;
    __syncthreads();
    for (int o = 1; o < 256; o <<= 1) {
        int tmp = (t >= o) ? s[t - o] : 0;
        __syncthreads();
        s[t] += tmp;
        __syncthreads();
    }
    cmat[b * NBLK + t] = s[t] - v;  // exclusive, bucket-local
    if (t == 255) btot[b] = s[255];
}

// in-LDS redundant exclusive scan of the 98 bucket totals (replaces the bscan launch).
// Writes sbe[0..NB2-1]; caller must __syncthreads()-free use after return (we sync inside).
static __device__ __forceinline__ void btot_exscan(const int* __restrict__ btot, int* sbi, int* sbe) {
    int t = threadIdx.x;
    int myv = 0;
    if (t < 128) {
        myv = (t < NB2) ? btot[t] : 0;
        sbi[t] = myv;
    }
    __syncthreads();
    for (int o = 1; o < 128; o <<= 1) {
        int tmp = (t >= o && t < 128) ? sbi[t - o] : 0;
        __syncthreads();
        if (t < 128) sbi[t] += tmp;
        __syncthreads();
    }
    if (t < NB2) sbe[t] = sbi[t] - myv;
    __syncthreads();
}

// D: scatter edges into exact bucket regions; cursors in LDS (block-private)
__global__ __launch_bounds__(256) void scatter_kernel(const void* __restrict__ raw,
                                                      const int* __restrict__ cmat,
                                                      const int* __restrict__ btot,
                                                      u32* __restrict__ pairs) {
    const bool wide = detect_wide(raw);
    __shared__ int sbi[128];
    __shared__ int sbe[NB2];
    __shared__ int cur[NB2];
    btot_exscan(btot, sbi, sbe);
    int t = threadIdx.x;
    if (t < NB2) cur[t] = cmat[t * NBLK + blockIdx.x] + sbe[t];
    __syncthreads();
    const int base = blockIdx.x * EPB;
    for (int i = t; i < EPB; i += 256) {
        int e = base + i;
        int s, d;
        if (wide) {
            const long long* p = (const long long*)raw;
            s = (int)p[e];
            d = (int)p[NEDGES + e];
        } else {
            const int* p = (const int*)raw;
            s = p[e];
            d = p[NEDGES + e];
        }
        int pos = atomicAdd(&cur[d >> B2SHIFT], 1);
        pairs[pos] = ((u32)(d & 511) << 16) | (u32)s;  // src < 50000 < 2^16
    }
}

// E: per-bucket degree count (LDS) + 512-wide LDS scan -> row_ptr + dinv
__global__ __launch_bounds__(256) void phase2a(const u32* __restrict__ pairs,
                                               const int* __restrict__ btot,
                                               int* __restrict__ row_ptr, float* __restrict__ dinv) {
    __shared__ int sbi[128];
    __shared__ int sbe[NB2];
    __shared__ int lcnt[512];
    __shared__ int ssc[512];
    int b = blockIdx.x, t = threadIdx.x;
    int n0 = b << B2SHIFT;
    btot_exscan(btot, sbi, sbe);
    lcnt[t] = 0; lcnt[t + 256] = 0;
    __syncthreads();
    int p0 = sbe[b], p1 = p0 + btot[b];
    for (int p = p0 + t; p < p1; p += 256)
        atomicAdd(&lcnt[pairs[p] >> 16], 1);
    __syncthreads();
    int c0 = lcnt[t], c1 = lcnt[t + 256];
    ssc[t] = c0; ssc[t + 256] = c1;
    __syncthreads();
    for (int o = 1; o < 512; o <<= 1) {
        int a0 = (t >= o) ? ssc[t - o] : 0;
        int a1 = ssc[t + 256 - o];  // t+256 >= o always (o <= 256)
        __syncthreads();
        ssc[t] += a0; ssc[t + 256] += a1;
        __syncthreads();
    }
    int na = n0 + t, nb = n0 + t + 256;
    if (na < NNODES) { row_ptr[na] = p0 + ssc[t] - c0;       dinv[na] = rsqrtf((float)c0 + 1.0f); }
    if (nb < NNODES) { row_ptr[nb] = p0 + ssc[t + 256] - c1; dinv[nb] = rsqrtf((float)c1 + 1.0f); }
    if (b == 0 && t == 0) row_ptr[NNODES] = NEDGES;
}

// F: per-bucket ranking -> packed (bf16(dinv[src])<<16 | src) stream
__global__ __launch_bounds__(256) void phase2b(const u32* __restrict__ pairs,
                                               const int* __restrict__ btot,
                                               const int* __restrict__ row_ptr, const float* __restrict__ dinv,
                                               u32* __restrict__ pw) {
    __shared__ int sbi[128];
    __shared__ int sbe[NB2];
    __shared__ int lcur[512];
    int b = blockIdx.x, t = threadIdx.x;
    int n0 = b << B2SHIFT;
    btot_exscan(btot, sbi, sbe);
    int na = n0 + t, nb = n0 + t + 256;
    lcur[t]       = (na < NNODES) ? row_ptr[na] : NEDGES;
    lcur[t + 256] = (nb < NNODES) ? row_ptr[nb] : NEDGES;
    __syncthreads();
    int p0 = sbe[b], p1 = p0 + btot[b];
    for (int p = p0 + t; p < p1; p += 256) {
        u32 pk = pairs[p];
        int dl = (int)(pk >> 16);
        int src = (int)(pk & 0xFFFFu);
        int pos = atomicAdd(&lcur[dl], 1);
        pw[pos] = ((u32)f2b(dinv[src]) << 16) | (u32)src;  // dinv L2-resident
    }
}

// ---------------- aggregation (round-6/9 best: unroll-8, clamped unconditional loads) ----------------
// out[v] = dv * ( dv*h[v] + sum_e w[e]*h[src[e]] ),  pw[e] = bf16(dinv[src])<<16 | src
template <int F>
__global__ __launch_bounds__(256) void agg_kernel(const u16* __restrict__ h,
                                                  const int* __restrict__ row_ptr,
                                                  const u32* __restrict__ pw,
                                                  const float* __restrict__ dinv,
                                                  u16* __restrict__ outb) {
    constexpr int VEC = F / 64;  // 2 (F=128) or 4 (F=256) bf16 per lane
    int lane = threadIdx.x & 63;
    int v = __builtin_amdgcn_readfirstlane((int)(blockIdx.x * 4 + (threadIdx.x >> 6)));
    const size_t lo = (size_t)lane * VEC;

    const int e0 = row_ptr[v], e1 = row_ptr[v + 1];
    float dv = dinv[v];
    float acc[VEC];
    {
        const u16* p = h + (size_t)v * F + lo;
        if constexpr (VEC == 4) {
            ushort4 t = *(const ushort4*)p;
            acc[0] = dv * b2f(t.x); acc[1] = dv * b2f(t.y); acc[2] = dv * b2f(t.z); acc[3] = dv * b2f(t.w);
        } else {
            ushort2 t = *(const ushort2*)p;
            acc[0] = dv * b2f(t.x); acc[1] = dv * b2f(t.y);
        }
    }
    // unconditional clamped unroll-8: all loads always issue (max MLP), OOB slots get w=0
    for (int e = e0; e < e1; e += 8) {
        u32 pk[8];
#pragma unroll
        for (int u = 0; u < 8; ++u) {
            int idx = e + u;
            pk[u] = pw[idx < e1 ? idx : e1 - 1];  // safe: loop entered only if e1 > e0
        }
        int   c[8];
        float w[8];
#pragma unroll
        for (int u = 0; u < 8; ++u) {
            c[u] = (int)(pk[u] & 0xFFFFu);
            w[u] = (e + u < e1) ? b2f((u16)(pk[u] >> 16)) : 0.0f;
        }
        if constexpr (VEC == 4) {
            ushort4 r[8];
#pragma unroll
            for (int u = 0; u < 8; ++u)
                r[u] = *(const ushort4*)(h + (size_t)c[u] * F + lo);
#pragma unroll
            for (int u = 0; u < 8; ++u) {
                acc[0] += w[u] * b2f(r[u].x);
                acc[1] += w[u] * b2f(r[u].y);
                acc[2] += w[u] * b2f(r[u].z);
                acc[3] += w[u] * b2f(r[u].w);
            }
        } else {
            ushort2 r[8];
#pragma unroll
            for (int u = 0; u < 8; ++u)
                r[u] = *(const ushort2*)(h + (size_t)c[u] * F + lo);
#pragma unroll
            for (int u = 0; u < 8; ++u) {
                acc[0] += w[u] * b2f(r[u].x);
                acc[1] += w[u] * b2f(r[u].y);
            }
        }
    }
    u16* o = outb + (size_t)v * F + lo;
    if constexpr (VEC == 4) {
        ushort4 t;
        t.x = f2b(dv * acc[0]); t.y = f2b(dv * acc[1]); t.z = f2b(dv * acc[2]); t.w = f2b(dv * acc[3]);
        *(ushort4*)o = t;
    } else {
        ushort2 t;
        t.x = f2b(dv * acc[0]); t.y = f2b(dv * acc[1]);
        *(ushort2*)o = t;
    }
}

// ---------------- bf16 MFMA GEMM: out[M x 256] = A[M x KT] @ W[KT x 256] + b ----------------
template <int KT, bool RELU, bool OUT_BF16>
__global__ __launch_bounds__(256) void gemm_mfma(const u16* __restrict__ A, const u16* __restrict__ Wt,
                                                 const float* __restrict__ bias, void* __restrict__ outp,
                                                 int M) {
    constexpr int BM = 128, BN = 128, BK = 32;
    __shared__ __align__(16) u16 As[BM * BK];
    __shared__ __align__(16) u16 Bs[BN * BK];
    const int tid = threadIdx.x;
    const int lane = tid & 63, wid = tid >> 6;
    const int l15 = lane & 15, lhi = lane >> 4;
    const int m0 = blockIdx.x * BM, n0 = blockIdx.y * BN;
    const int wr = (wid >> 1) * 64, wc = (wid & 1) * 64;

    f32x4 acc[4][4] = {};

    const int sr = tid >> 1;        // staging row 0..127
    const int sc2 = (tid & 1) * 2;  // staging chunk base (0 or 2)

    for (int k0 = 0; k0 < KT; k0 += BK) {
        uint4 av0, av1, bv0, bv1;
        int ar = m0 + sr;
        if (ar < M) {
            const uint4* ap = (const uint4*)(A + (size_t)ar * KT + k0 + sc2 * 8);
            av0 = ap[0]; av1 = ap[1];
        } else {
            av0 = make_uint4(0, 0, 0, 0); av1 = av0;
        }
        const uint4* bp = (const uint4*)(Wt + (size_t)(n0 + sr) * KT + k0 + sc2 * 8);
        bv0 = bp[0]; bv1 = bp[1];

        __syncthreads();
        *(uint4*)&As[sr * BK + ((sc2 ^ (sr & 3)) * 8)]       = av0;
        *(uint4*)&As[sr * BK + (((sc2 + 1) ^ (sr & 3)) * 8)] = av1;
        *(uint4*)&Bs[sr * BK + ((sc2 ^ (sr & 3)) * 8)]       = bv0;
        *(uint4*)&Bs[sr * BK + (((sc2 + 1) ^ (sr & 3)) * 8)] = bv1;
        __syncthreads();

        s16x8 af[4], bfr[4];
#pragma unroll
        for (int m = 0; m < 4; ++m) {
            int r = wr + m * 16 + l15;
            af[m] = *(const s16x8*)&As[r * BK + ((lhi ^ (r & 3)) * 8)];
        }
#pragma unroll
        for (int n = 0; n < 4; ++n) {
            int r = wc + n * 16 + l15;
            bfr[n] = *(const s16x8*)&Bs[r * BK + ((lhi ^ (r & 3)) * 8)];
        }
#pragma unroll
        for (int m = 0; m < 4; ++m)
#pragma unroll
            for (int n = 0; n < 4; ++n)
                acc[m][n] = __builtin_amdgcn_mfma_f32_16x16x32_bf16(af[m], bfr[n], acc[m][n], 0, 0, 0);
    }

    // epilogue: C/D layout col = lane&15, row = (lane>>4)*4 + reg
#pragma unroll
    for (int n = 0; n < 4; ++n) {
        int gcol = n0 + wc + n * 16 + l15;
        float bb = bias[gcol];
#pragma unroll
        for (int m = 0; m < 4; ++m) {
            int gr0 = m0 + wr + m * 16 + lhi * 4;
#pragma unroll
            for (int r = 0; r < 4; ++r) {
                int gr = gr0 + r;
                if (gr >= M) continue;
                float vv = acc[m][n][r] + bb;
                if (RELU) vv = vv > 0.f ? vv : 0.f;
                if (OUT_BF16)
                    ((u16*)outp)[(size_t)gr * 256 + gcol] = f2b(vv);
                else
                    ((float*)outp)[(size_t)gr * 256 + gcol] = vv;
            }
        }
    }
}

// ---------------- launch ----------------
extern "C" void kernel_launch(void* const* d_in, const int* in_sizes, int n_in,
                              void* d_out, int out_size, void* d_ws, size_t ws_size,
                              hipStream_t stream) {
    const float* x  = (const float*)d_in[0];
    const void* edges = d_in[1];
    const float* W1 = (const float*)d_in[2];
    const float* b1 = (const float*)d_in[3];
    const float* W2 = (const float*)d_in[4];
    const float* b2 = (const float*)d_in[5];
    const float* W3 = (const float*)d_in[6];
    const float* b3 = (const float*)d_in[7];
    float* out = (float*)d_out;

    char* ws = (char*)d_ws;
    float* dinv   = (float*)(ws + OFF_DINV);
    int*   rowptr = (int*)(ws + OFF_ROWPTR);
    int*   cmat   = (int*)(ws + OFF_CMAT);
    int*   btot   = (int*)(ws + OFF_BTOT);
    u32*   pairs  = (u32*)(ws + OFF_PAIRS);
    u32*   pw     = (u32*)(ws + OFF_PW);
    u16*   xb     = (u16*)(ws + OFF_XB);
    u16*   hb     = (u16*)(ws + OFF_HB);
    u16*   aggb   = (u16*)(ws + OFF_AGGB);
    u16*   W1t    = (u16*)(ws + OFF_W1T);
    u16*   W2t    = (u16*)(ws + OFF_W2T);
    u16*   W3t    = (u16*)(ws + OFF_W3T);

    // CSR build + converts (hist+convert merged; bucket-base scan inlined into consumers)
    hist_conv<<<NBLK + 6250 + 640, 256, 0, stream>>>(edges, cmat, x, W1, W2, W3, xb, W1t, W2t, W3t);
    offset_kernel<<<NB2, 256, 0, stream>>>(cmat, btot);
    scatter_kernel<<<NBLK, 256, 0, stream>>>(edges, cmat, btot, pairs);
    phase2a<<<NB2, 256, 0, stream>>>(pairs, btot, rowptr, dinv);
    phase2b<<<NB2, 256, 0, stream>>>(pairs, btot, rowptr, dinv, pw);

    const int AGG_GRID = NNODES / 4;  // 12500
    dim3 ggrid((NNODES + 127) / 128, 2);

    // layer 1
    agg_kernel<F_IN><<<AGG_GRID, 256, 0, stream>>>(xb, rowptr, pw, dinv, aggb);
    gemm_mfma<F_IN, true, true><<<ggrid, 256, 0, stream>>>(aggb, W1t, b1, hb, NNODES);

    // layer 2
    agg_kernel<F_HID><<<AGG_GRID, 256, 0, stream>>>(hb, rowptr, pw, dinv, aggb);
    gemm_mfma<F_HID, true, true><<<ggrid, 256, 0, stream>>>(aggb, W2t, b2, hb, NNODES);

    // layer 3
    agg_kernel<F_HID><<<AGG_GRID, 256, 0, stream>>>(hb, rowptr, pw, dinv, aggb);
    gemm_mfma<F_HID, false, false><<<ggrid, 256, 0, stream>>>(aggb, W3t, b3, out, NNODES);
}